// Round 2
// baseline (3365.958 us; speedup 1.0000x reference)
//
#include <hip/hip_runtime.h>

// Problem constants (match reference setup_inputs / module hyperparams)
#define BATCH 4
#define HGT   720
#define WID   1280
#define HW    (HGT * WID)           // 921600
#define NPIX  (BATCH * HW)          // 3686400
#define INV2S2 0.22222222222222222f // 1/(2*1.5^2)
#define INV_LAMBDA_E (255.0f / 30.0f)
#define THRESH 1e-6f
#define EPSV   1e-6f

// Scatter-splat tiling: each block owns a 16x16 output tile accumulated in
// LDS. Threads scatter the (16+2*GM)^2 halo sources' 16 taps into the tile
// with ds_add_f32 (LDS atomics) — work scales with HITS, not with a scan
// window, so CUT can be large. Margin rule: a tap of source s lands at
// tap - s in (u-2, u+2], |u| < CUT = 4  =>  |tap - s| <= 5  =>  GM = 5.
// Sources with |u| or |v| >= CUT (~470 px/launch at CUT=4, P~1.27e-4) go to
// outlier_kernel (global atomics AFTER the owner stores).
#define GT   16
#define GM   5
#define GE   (GT + 2 * GM)   // 26
#define GEC  (GE * GE)       // 676 halo sources per block
#define CUT  4.0f

// ---------------------------------------------------------------------------
// Kernel 1: photometric error = mean_c |i1 - warp(i2, flow)|   -> err [N]
// ---------------------------------------------------------------------------
__global__ __launch_bounds__(256) void err_kernel(
    const float* __restrict__ i1, const float* __restrict__ i2,
    const float* __restrict__ flow, float* __restrict__ err) {
  int n = blockIdx.x * blockDim.x + threadIdx.x;
  if (n >= NPIX) return;
  int b = n / HW;
  int r = n - b * HW;
  int y = r / WID;
  int x = r - y * WID;

  float u = flow[(b * 2 + 0) * HW + r];
  float v = flow[(b * 2 + 1) * HW + r];
  float gx = fminf(fmaxf((float)x + u, 0.0f), (float)(WID - 1));
  float gy = fminf(fmaxf((float)y + v, 0.0f), (float)(HGT - 1));
  float x0f = floorf(gx), y0f = floorf(gy);
  int x0 = (int)x0f, y0 = (int)y0f;
  int x1 = min(x0 + 1, WID - 1), y1 = min(y0 + 1, HGT - 1);
  float wx = gx - x0f, wy = gy - y0f;
  float w00 = (1.0f - wx) * (1.0f - wy);
  float w01 = wx * (1.0f - wy);
  float w10 = (1.0f - wx) * wy;
  float w11 = wx * wy;
  int i00 = y0 * WID + x0, i01 = y0 * WID + x1;
  int i10 = y1 * WID + x0, i11 = y1 * WID + x1;

  const float* i2b = i2 + (size_t)b * 3 * HW;
  const float* i1b = i1 + (size_t)b * 3 * HW;
  float s = 0.0f;
#pragma unroll
  for (int c = 0; c < 3; ++c) {
    const float* p = i2b + c * HW;
    float wv = p[i00] * w00 + p[i01] * w01 + p[i10] * w10 + p[i11] * w11;
    s += fabsf(i1b[c * HW + r] - wv);
  }
  err[n] = s * (1.0f / 3.0f);
}

// ---------------------------------------------------------------------------
// Kernel 2: 3x3 zero-padded box filter of err, then fw = exp(-(e/LE)^2)
// ---------------------------------------------------------------------------
__global__ __launch_bounds__(256) void fw_kernel(
    const float* __restrict__ err, float* __restrict__ fw) {
  int n = blockIdx.x * blockDim.x + threadIdx.x;
  if (n >= NPIX) return;
  int b = n / HW;
  int r = n - b * HW;
  int y = r / WID;
  int x = r - y * WID;
  const float* e = err + (size_t)b * HW;
  float s = 0.0f;
#pragma unroll
  for (int dy = -1; dy <= 1; ++dy) {
    int yy = y + dy;
    if (yy < 0 || yy >= HGT) continue;
#pragma unroll
    for (int dx = -1; dx <= 1; ++dx) {
      int xx = x + dx;
      if (xx < 0 || xx >= WID) continue;
      s += e[yy * WID + xx];
    }
  }
  s *= (1.0f / 9.0f);
  float t = s * INV_LAMBDA_E;
  fw[n] = expf(-t * t);   // LAMBDA_V == 1
}

// ---------------------------------------------------------------------------
// Kernel 3: LDS-scatter gaussian splat.
// Block owns a 16x16 tile; acc[5][256] in LDS (p0,p1,p2,pw,rw planes).
// Each thread takes halo sources i = tid, tid+256, ... (GEC = 676), reads
// flow/img/fw straight from global (halo re-reads hit L1/L2), and scatters
// the source's 16 taps into the tile via atomicAdd on LDS (ds_add_f32).
// Taps outside the tile belong to (exactly one) neighboring tile and are
// skipped here — each (source, tap) pair is processed exactly once on chip.
// Bit-exactness vs reference per term:
//   tx    = (float)sx + u                    (same op as reference)
//   fracx = tx - floorf(tx)                  (exact, Sterbenz)
//   ddx   = fracx - (float)(dx-1)            (one correctly-rounded op on the
//            same exact value as reference's tx - ix  => bitwise identical)
//   g     = __expf(-(ddx^2+ddy^2)*INV2S2)    (fused, as before)
// TAO_R truncation is dead (min in-window g = exp(-8/4.5) = 0.169 > 0.05).
// Only the summation ORDER differs from the gather version (LDS atomics).
// ---------------------------------------------------------------------------
__global__ __launch_bounds__(256) void splat_scatter_kernel(
    const float* __restrict__ flow, const float* __restrict__ img,
    const float* __restrict__ fw, float* __restrict__ p,
    float* __restrict__ pw, float* __restrict__ rw) {
  __shared__ float acc[5 * 256];

  const int b = blockIdx.z;
  const int tx0 = blockIdx.x * GT;
  const int ty0 = blockIdx.y * GT;
  const int ex0 = tx0 - GM;
  const int ey0 = ty0 - GM;

#pragma unroll
  for (int k = 0; k < 5; ++k) acc[k * 256 + threadIdx.x] = 0.0f;
  __syncthreads();

  const float* fu  = flow + (size_t)(b * 2 + 0) * HW;
  const float* fv  = flow + (size_t)(b * 2 + 1) * HW;
  const float* ib  = img + (size_t)b * 3 * HW;
  const float* fwb = fw + (size_t)b * HW;

  for (int i = threadIdx.x; i < GEC; i += 256) {
    int sly = i / GE, slx = i - sly * GE;
    int sx = ex0 + slx, sy = ey0 + sly;
    if (sx < 0 || sx >= WID || sy < 0 || sy >= HGT) continue;
    int r = sy * WID + sx;
    float u = fu[r], v = fv[r];
    if (!(fabsf(u) < CUT && fabsf(v) < CUT)) continue;  // outlier_kernel's job

    float tx = (float)sx + u;
    float ty = (float)sy + v;
    float fx = floorf(tx), fy = floorf(ty);
    int ix0 = (int)fx, iy0 = (int)fy;
    float fracx = tx - fx, fracy = ty - fy;   // exact

    float fwv = fwb[r];
    float s0 = ib[r] * fwv;
    float s1 = ib[HW + r] * fwv;
    float s2 = ib[2 * HW + r] * fwv;

#pragma unroll
    for (int dy = 0; dy < 4; ++dy) {
      int py = iy0 + (dy - 1) - ty0;          // tile-local tap y
      if (py < 0 || py >= GT) continue;
      float ddy = fracy - (float)(dy - 1);
      float ddy2 = ddy * ddy;
#pragma unroll
      for (int dx = 0; dx < 4; ++dx) {
        int px = ix0 + (dx - 1) - tx0;        // tile-local tap x
        if (px < 0 || px >= GT) continue;
        float ddx = fracx - (float)(dx - 1);
        float g = __expf(-(ddx * ddx + ddy2) * INV2S2);
        int li = py * GT + px;
        atomicAdd(&acc[0 * 256 + li], s0 * g);
        atomicAdd(&acc[1 * 256 + li], s1 * g);
        atomicAdd(&acc[2 * 256 + li], s2 * g);
        atomicAdd(&acc[3 * 256 + li], fwv * g);
        atomicAdd(&acc[4 * 256 + li], g);
      }
    }
  }
  __syncthreads();

  // ---- plain coalesced stores: sole owner of this output tile ----
  const int lx = threadIdx.x & 15;
  const int ly = threadIdx.x >> 4;
  const int gi = b * HW + (ty0 + ly) * WID + tx0 + lx;
  p[gi]            = acc[0 * 256 + threadIdx.x];
  p[NPIX + gi]     = acc[1 * 256 + threadIdx.x];
  p[2 * NPIX + gi] = acc[2 * 256 + threadIdx.x];
  pw[gi]           = acc[3 * 256 + threadIdx.x];
  rw[gi]           = acc[4 * 256 + threadIdx.x];
}

// ---------------------------------------------------------------------------
// Kernel 3b: outlier splat — pixels with |flow| >= CUT (~470 px/launch at
// CUT=4.0) via direct global atomics. Runs AFTER splat_scatter (owner stores
// done). Separable exp differs from the fused-exp path by ~1 ulp.
// ---------------------------------------------------------------------------
__global__ __launch_bounds__(256) void outlier_kernel(
    const float* __restrict__ flow, const float* __restrict__ img,
    const float* __restrict__ fw, float* __restrict__ p,
    float* __restrict__ pw, float* __restrict__ rw) {
  int n = blockIdx.x * blockDim.x + threadIdx.x;
  if (n >= NPIX) return;
  int b = n / HW;
  int r = n - b * HW;
  float u = flow[(b * 2 + 0) * HW + r];
  float v = flow[(b * 2 + 1) * HW + r];
  if (fabsf(u) < CUT && fabsf(v) < CUT) return;  // complementary to scatter

  int y = r / WID;
  int x = r - y * WID;
  float txf = (float)x + u, tyf = (float)y + v;
  float fx = floorf(txf), fy = floorf(tyf);
  int ixb = (int)fx, iyb = (int)fy;
  float fracx = txf - fx, fracy = tyf - fy;

  float gxv[4], gyv[4];
#pragma unroll
  for (int d = 0; d < 4; ++d) {
    float ddx = fracx - (float)(d - 1);
    gxv[d] = __expf(-ddx * ddx * INV2S2);
    float ddy = fracy - (float)(d - 1);
    gyv[d] = __expf(-ddy * ddy * INV2S2);
  }

  float fwv = fw[n];
  const float* ib = img + (size_t)b * 3 * HW;
  float s0 = ib[0 * HW + r] * fwv;
  float s1 = ib[1 * HW + r] * fwv;
  float s2 = ib[2 * HW + r] * fwv;

  int base = b * HW;
  for (int dy = 0; dy < 4; ++dy) {
    int iy = iyb + dy - 1;
    if (iy < 0 || iy >= HGT) continue;
    float gy = gyv[dy];
    for (int dx = 0; dx < 4; ++dx) {
      int ix = ixb + dx - 1;
      if (ix < 0 || ix >= WID) continue;
      float g = gxv[dx] * gy;
      int gi = base + iy * WID + ix;
      atomicAdd(p + gi, s0 * g);
      atomicAdd(p + NPIX + gi, s1 * g);
      atomicAdd(p + 2 * NPIX + gi, s2 * g);
      atomicAdd(pw + gi, fwv * g);
      atomicAdd(rw + gi, g);
    }
  }
}

// ---------------------------------------------------------------------------
// Kernel 4a: branch-1 accumulate: out = i1*w1 (write), den = w1 (write)
// ---------------------------------------------------------------------------
__global__ __launch_bounds__(256) void acc1_kernel(
    const float* __restrict__ p, const float* __restrict__ pw,
    const float* __restrict__ rw, float* __restrict__ out,
    float* __restrict__ den) {
  int n = blockIdx.x * blockDim.x + threadIdx.x;
  if (n >= NPIX) return;
  int b = n / HW;
  int r = n - b * HW;
  float pwv = pw[n], rwv = rw[n];
  float w = pwv / (rwv + THRESH);
  den[n] = w;
  float scale = w / (pwv + THRESH);
  int ob = b * 3 * HW + r;
  out[ob + 0 * HW] = p[n] * scale;
  out[ob + 1 * HW] = p[NPIX + n] * scale;
  out[ob + 2 * HW] = p[2 * NPIX + n] * scale;
}

// ---------------------------------------------------------------------------
// Kernel 4b: branch-2 accumulate + final blend:
//   out = (out + i2*w2) / (den + w2 + EPS)
// ---------------------------------------------------------------------------
__global__ __launch_bounds__(256) void acc2_kernel(
    const float* __restrict__ p, const float* __restrict__ pw,
    const float* __restrict__ rw, const float* __restrict__ den,
    float* __restrict__ out) {
  int n = blockIdx.x * blockDim.x + threadIdx.x;
  if (n >= NPIX) return;
  int b = n / HW;
  int r = n - b * HW;
  float pwv = pw[n], rwv = rw[n];
  float w = pwv / (rwv + THRESH);
  float scale = w / (pwv + THRESH);
  float d = den[n] + w + EPSV;
  float invd = 1.0f / d;
  int ob = b * 3 * HW + r;
  out[ob + 0 * HW] = (out[ob + 0 * HW] + p[n] * scale) * invd;
  out[ob + 1 * HW] = (out[ob + 1 * HW] + p[NPIX + n] * scale) * invd;
  out[ob + 2 * HW] = (out[ob + 2 * HW] + p[2 * NPIX + n] * scale) * invd;
}

// ---------------------------------------------------------------------------
// Launcher. Workspace layout (floats), 7N total = 103.2 MB:
//   [0, 3N)   p (3 planes); p[0] aliases err scratch (consumed before splat)
//   [3N, 4N)  pw   [4N, 5N)  rw   [5N, 6N)  fw   [6N, 7N)  den (w1)
// No memsets: scatter stores fully initialize p/pw/rw before any read.
// ---------------------------------------------------------------------------
extern "C" void kernel_launch(void* const* d_in, const int* in_sizes, int n_in,
                              void* d_out, int out_size, void* d_ws,
                              size_t ws_size, hipStream_t stream) {
  const float* input1 = (const float*)d_in[0];
  const float* input2 = (const float*)d_in[1];
  const float* flow3  = (const float*)d_in[2];
  const float* flow4  = (const float*)d_in[3];
  float* out = (float*)d_out;

  float* ws  = (float*)d_ws;
  float* p   = ws;
  float* err = ws;
  float* pw  = ws + (size_t)3 * NPIX;
  float* rw  = ws + (size_t)4 * NPIX;
  float* fw  = ws + (size_t)5 * NPIX;
  float* den = ws + (size_t)6 * NPIX;

  const int threads = 256;
  const int blocks = (NPIX + threads - 1) / threads;
  dim3 sgrid(WID / GT, HGT / GT, BATCH);  // 80 x 45 x 4, all tiles full

  // ---- branch 1: warp input2 by flow3, compare to input1, splat input1 ----
  err_kernel<<<blocks, threads, 0, stream>>>(input1, input2, flow3, err);
  fw_kernel<<<blocks, threads, 0, stream>>>(err, fw);
  splat_scatter_kernel<<<sgrid, threads, 0, stream>>>(flow3, input1, fw, p, pw, rw);
  outlier_kernel<<<blocks, threads, 0, stream>>>(flow3, input1, fw, p, pw, rw);
  acc1_kernel<<<blocks, threads, 0, stream>>>(p, pw, rw, out, den);

  // ---- branch 2: warp input1 by flow4, compare to input2, splat input2 ----
  err_kernel<<<blocks, threads, 0, stream>>>(input2, input1, flow4, err);
  fw_kernel<<<blocks, threads, 0, stream>>>(err, fw);
  splat_scatter_kernel<<<sgrid, threads, 0, stream>>>(flow4, input2, fw, p, pw, rw);
  outlier_kernel<<<blocks, threads, 0, stream>>>(flow4, input2, fw, p, pw, rw);
  acc2_kernel<<<blocks, threads, 0, stream>>>(p, pw, rw, den, out);
}

// Round 3
// 574.122 us; speedup vs baseline: 5.8628x; 5.8628x over previous
//
#include <hip/hip_runtime.h>

// Problem constants (match reference setup_inputs / module hyperparams)
#define BATCH 4
#define HGT   720
#define WID   1280
#define HW    (HGT * WID)           // 921600
#define NPIX  (BATCH * HW)          // 3686400
#define INV2S2 0.22222222222222222f // 1/(2*1.5^2)
#define INV_LAMBDA_E (255.0f / 30.0f)
#define THRESH 1e-6f
#define EPSV   1e-6f

// Binned-gather splat tiling. Each block owns a 16x16 output tile. Staged
// halo sources are BINNED by their integer target cell floor(tx),floor(ty)
// (19x19 cells cover floors [t0-2, t0+16] — exactly the floors whose 4x4 tap
// box intersects the tile). Each output lane then gathers ONLY the entries
// in the 16 cells of its tap window (4 contiguous per-row ranges) — work
// scales with true hits (~16/output), not with a scan window.
// Halo: source sx can have floor(tx) in [t0-2, t0+16] with |u| < CUT=4 iff
// sx in [t0-5, t0+20]  =>  GM = 5, GE = 26.
// Row-list capacity: floor(ty)=F reachable only from sy in [F-3, F+4]
// (8 rows) x 26 cols = 208  => ECAP=208 is a HARD bound, no overflow path.
#define GT    16
#define GM    5
#define GE    (GT + 2 * GM)   // 26
#define GEC   (GE * GE)       // 676 halo sources per block
#define CUT   4.0f
#define CELLS 19              // floor values t0-2 .. t0+16
#define SCOL  20              // per-row starts: cells 0..18 + row total
#define ECAP  208             // hard max entries per cell-row

// ---------------------------------------------------------------------------
// Kernel 1: photometric error = mean_c |i1 - warp(i2, flow)|   -> err [N]
// ---------------------------------------------------------------------------
__global__ __launch_bounds__(256) void err_kernel(
    const float* __restrict__ i1, const float* __restrict__ i2,
    const float* __restrict__ flow, float* __restrict__ err) {
  int n = blockIdx.x * blockDim.x + threadIdx.x;
  if (n >= NPIX) return;
  int b = n / HW;
  int r = n - b * HW;
  int y = r / WID;
  int x = r - y * WID;

  float u = flow[(b * 2 + 0) * HW + r];
  float v = flow[(b * 2 + 1) * HW + r];
  float gx = fminf(fmaxf((float)x + u, 0.0f), (float)(WID - 1));
  float gy = fminf(fmaxf((float)y + v, 0.0f), (float)(HGT - 1));
  float x0f = floorf(gx), y0f = floorf(gy);
  int x0 = (int)x0f, y0 = (int)y0f;
  int x1 = min(x0 + 1, WID - 1), y1 = min(y0 + 1, HGT - 1);
  float wx = gx - x0f, wy = gy - y0f;
  float w00 = (1.0f - wx) * (1.0f - wy);
  float w01 = wx * (1.0f - wy);
  float w10 = (1.0f - wx) * wy;
  float w11 = wx * wy;
  int i00 = y0 * WID + x0, i01 = y0 * WID + x1;
  int i10 = y1 * WID + x0, i11 = y1 * WID + x1;

  const float* i2b = i2 + (size_t)b * 3 * HW;
  const float* i1b = i1 + (size_t)b * 3 * HW;
  float s = 0.0f;
#pragma unroll
  for (int c = 0; c < 3; ++c) {
    const float* p = i2b + c * HW;
    float wv = p[i00] * w00 + p[i01] * w01 + p[i10] * w10 + p[i11] * w11;
    s += fabsf(i1b[c * HW + r] - wv);
  }
  err[n] = s * (1.0f / 3.0f);
}

// ---------------------------------------------------------------------------
// Kernel 2: 3x3 zero-padded box filter of err, then fw = exp(-(e/LE)^2)
// ---------------------------------------------------------------------------
__global__ __launch_bounds__(256) void fw_kernel(
    const float* __restrict__ err, float* __restrict__ fw) {
  int n = blockIdx.x * blockDim.x + threadIdx.x;
  if (n >= NPIX) return;
  int b = n / HW;
  int r = n - b * HW;
  int y = r / WID;
  int x = r - y * WID;
  const float* e = err + (size_t)b * HW;
  float s = 0.0f;
#pragma unroll
  for (int dy = -1; dy <= 1; ++dy) {
    int yy = y + dy;
    if (yy < 0 || yy >= HGT) continue;
#pragma unroll
    for (int dx = -1; dx <= 1; ++dx) {
      int xx = x + dx;
      if (xx < 0 || xx >= WID) continue;
      s += e[yy * WID + xx];
    }
  }
  s *= (1.0f / 9.0f);
  float t = s * INV_LAMBDA_E;
  fw[n] = expf(-t * t);   // LAMBDA_V == 1
}

// ---------------------------------------------------------------------------
// Kernel 3: BINNED-gather gaussian splat — zero global atomics, light LDS
// atomics (1 low-contention ds_add per SOURCE for binning; round-2's failure
// was ~30 contended ds_adds per source on accumulator taps).
// Phases: (0) zero counts  (1) stage sources: frac+premultiplied vals indexed
// by halo slot, count per target cell  (2) per-row prefix (20 cells, serial
// per thread, parallel over 380 cells)  (3) fill entry lists (u16 = cx<<10 |
// slot), position = rowstart(cell)+ofs, provably < ECAP  (4) each lane walks
// 4 contiguous ranges covering its 4x4 tap window, accumulating in regs.
// Bit-exactness per term (same as round-1 path, passed at absmax 4e-3):
//   tx    = (float)sx + u            (identical op to reference)
//   fracx = tx - floorf(tx)          (exact)
//   ddx   = fracx - (float)(dx-1)    (one rounding, == reference's tx - ix)
//   g     = __expf(-(ddx*ddx+ddy*ddy)*INV2S2)
// Only summation order differs (cell/atomic order). TAO_R truncation dead
// (min in-window g = exp(-8/4.5) = 0.169 > 0.05).
// ---------------------------------------------------------------------------
__global__ __launch_bounds__(256) void splat_binned_kernel(
    const float* __restrict__ flow, const float* __restrict__ img,
    const float* __restrict__ fw, float* __restrict__ p,
    float* __restrict__ pw, float* __restrict__ rw) {
  __shared__ float2 sfrac[GEC];                    //  5408 B
  __shared__ float4 sval[GEC];                     // 10816 B
  __shared__ unsigned short sent[CELLS * ECAP];    //  7904 B
  __shared__ unsigned int scnt[CELLS * CELLS];     //  1444 B
  __shared__ unsigned int sstart[CELLS * SCOL];    //  1520 B   ~27 KB total

  const int b = blockIdx.z;
  const int tx0 = blockIdx.x * GT;
  const int ty0 = blockIdx.y * GT;
  const int ex0 = tx0 - GM;
  const int ey0 = ty0 - GM;
  const float* fu  = flow + (size_t)(b * 2 + 0) * HW;
  const float* fv  = flow + (size_t)(b * 2 + 1) * HW;
  const float* ib  = img + (size_t)b * 3 * HW;
  const float* fwb = fw + (size_t)b * HW;

  // ---- phase 0: zero cell counts ----
  for (int i = threadIdx.x; i < CELLS * CELLS; i += 256) scnt[i] = 0u;
  __syncthreads();

  // ---- phase 1: stage + count (<=3 sources/thread, statically unrolled) ----
  int mycell[3];
  unsigned int myofs[3];
#pragma unroll
  for (int t = 0; t < 3; ++t) {
    int cell = -1;
    unsigned int ofs = 0;
    int i = threadIdx.x + t * 256;
    if (i < GEC) {
      int sly = i / GE, slx = i - sly * GE;
      int sx = ex0 + slx, sy = ey0 + sly;
      if (sx >= 0 && sx < WID && sy >= 0 && sy < HGT) {
        int r = sy * WID + sx;
        float u = fu[r], v = fv[r];
        if (fabsf(u) < CUT && fabsf(v) < CUT) {  // complement of outlier path
          float tx = (float)sx + u;
          float ty = (float)sy + v;
          float fx = floorf(tx), fy = floorf(ty);
          int cx = (int)fx - (tx0 - 2);
          int cy = (int)fy - (ty0 - 2);
          if (cx >= 0 && cx < CELLS && cy >= 0 && cy < CELLS) {
            float fwv = fwb[r];
            sfrac[i] = make_float2(tx - fx, ty - fy);
            sval[i] = make_float4(ib[r] * fwv, ib[HW + r] * fwv,
                                  ib[2 * HW + r] * fwv, fwv);
            cell = cy * CELLS + cx;
            ofs = atomicAdd(&scnt[cell], 1u);
          }
        }
      }
    }
    mycell[t] = cell;
    myofs[t] = ofs;
  }
  __syncthreads();

  // ---- phase 2: per-row exclusive prefix over 19 cells (+ row total) ----
  for (int c = threadIdx.x; c < CELLS * SCOL; c += 256) {
    int cy = c / SCOL, cx = c - cy * SCOL;
    unsigned int s = 0;
    for (int q = 0; q < cx; ++q) s += scnt[cy * CELLS + q];
    sstart[c] = s;
  }
  __syncthreads();

  // ---- phase 3: fill entry lists (pos provably < ECAP) ----
#pragma unroll
  for (int t = 0; t < 3; ++t) {
    if (mycell[t] >= 0) {
      int cy = mycell[t] / CELLS, cx = mycell[t] - cy * CELLS;
      unsigned int pos = sstart[cy * SCOL + cx] + myofs[t];
      sent[cy * ECAP + pos] =
          (unsigned short)(((unsigned)cx << 10) | (unsigned)(threadIdx.x + t * 256));
    }
  }
  __syncthreads();

  // ---- phase 4: gather own tap window (4 contiguous ranges) ----
  const int lx = threadIdx.x & 15;
  const int ly = threadIdx.x >> 4;
  float a0 = 0.f, a1 = 0.f, a2 = 0.f, apw = 0.f, arw = 0.f;

#pragma unroll
  for (int k = 0; k < 4; ++k) {
    const int cy = ly + k;                    // cell rows ly..ly+3
    int s = (int)sstart[cy * SCOL + lx];      // cells lx..lx+3 contiguous
    int e = (int)sstart[cy * SCOL + lx + 4];
    const float cky = (float)(2 - k);         // ddy = fracy - (dy-1), dy=3-k
    const int ebase = cy * ECAP;
    for (int j = s; j < e; ++j) {
      unsigned int en = sent[ebase + j];
      int slot = en & 1023;
      int cx = en >> 10;
      float2 fr = sfrac[slot];
      float ddx = fr.x - (float)(lx - cx + 2); // fracx - (dx-1), dx=lx-cx+3
      float ddy = fr.y - cky;
      float g = __expf(-(ddx * ddx + ddy * ddy) * INV2S2);
      float4 vl = sval[slot];
      a0 += vl.x * g;
      a1 += vl.y * g;
      a2 += vl.z * g;
      apw += vl.w * g;
      arw += g;
    }
  }

  // ---- plain coalesced stores: sole owner of this output pixel ----
  const int gi = b * HW + (ty0 + ly) * WID + tx0 + lx;
  p[gi]            = a0;
  p[NPIX + gi]     = a1;
  p[2 * NPIX + gi] = a2;
  pw[gi]           = apw;
  rw[gi]           = arw;
}

// ---------------------------------------------------------------------------
// Kernel 3b: outlier splat — pixels with |flow| >= CUT (~470 px/launch at
// CUT=4.0, P ~ 1.27e-4) via direct global atomics. Runs AFTER splat_binned
// (owner stores done). Separable exp differs from fused path by ~1 ulp.
// ---------------------------------------------------------------------------
__global__ __launch_bounds__(256) void outlier_kernel(
    const float* __restrict__ flow, const float* __restrict__ img,
    const float* __restrict__ fw, float* __restrict__ p,
    float* __restrict__ pw, float* __restrict__ rw) {
  int n = blockIdx.x * blockDim.x + threadIdx.x;
  if (n >= NPIX) return;
  int b = n / HW;
  int r = n - b * HW;
  float u = flow[(b * 2 + 0) * HW + r];
  float v = flow[(b * 2 + 1) * HW + r];
  if (fabsf(u) < CUT && fabsf(v) < CUT) return;  // complementary to binning

  int y = r / WID;
  int x = r - y * WID;
  float txf = (float)x + u, tyf = (float)y + v;
  float fx = floorf(txf), fy = floorf(tyf);
  int ixb = (int)fx, iyb = (int)fy;
  float fracx = txf - fx, fracy = tyf - fy;

  float gxv[4], gyv[4];
#pragma unroll
  for (int d = 0; d < 4; ++d) {
    float ddx = fracx - (float)(d - 1);
    gxv[d] = __expf(-ddx * ddx * INV2S2);
    float ddy = fracy - (float)(d - 1);
    gyv[d] = __expf(-ddy * ddy * INV2S2);
  }

  float fwv = fw[n];
  const float* ib = img + (size_t)b * 3 * HW;
  float s0 = ib[0 * HW + r] * fwv;
  float s1 = ib[1 * HW + r] * fwv;
  float s2 = ib[2 * HW + r] * fwv;

  int base = b * HW;
  for (int dy = 0; dy < 4; ++dy) {
    int iy = iyb + dy - 1;
    if (iy < 0 || iy >= HGT) continue;
    float gy = gyv[dy];
    for (int dx = 0; dx < 4; ++dx) {
      int ix = ixb + dx - 1;
      if (ix < 0 || ix >= WID) continue;
      float g = gxv[dx] * gy;
      int gi = base + iy * WID + ix;
      atomicAdd(p + gi, s0 * g);
      atomicAdd(p + NPIX + gi, s1 * g);
      atomicAdd(p + 2 * NPIX + gi, s2 * g);
      atomicAdd(pw + gi, fwv * g);
      atomicAdd(rw + gi, g);
    }
  }
}

// ---------------------------------------------------------------------------
// Kernel 4a: branch-1 accumulate: out = i1*w1 (write), den = w1 (write)
// ---------------------------------------------------------------------------
__global__ __launch_bounds__(256) void acc1_kernel(
    const float* __restrict__ p, const float* __restrict__ pw,
    const float* __restrict__ rw, float* __restrict__ out,
    float* __restrict__ den) {
  int n = blockIdx.x * blockDim.x + threadIdx.x;
  if (n >= NPIX) return;
  int b = n / HW;
  int r = n - b * HW;
  float pwv = pw[n], rwv = rw[n];
  float w = pwv / (rwv + THRESH);
  den[n] = w;
  float scale = w / (pwv + THRESH);
  int ob = b * 3 * HW + r;
  out[ob + 0 * HW] = p[n] * scale;
  out[ob + 1 * HW] = p[NPIX + n] * scale;
  out[ob + 2 * HW] = p[2 * NPIX + n] * scale;
}

// ---------------------------------------------------------------------------
// Kernel 4b: branch-2 accumulate + final blend:
//   out = (out + i2*w2) / (den + w2 + EPS)
// ---------------------------------------------------------------------------
__global__ __launch_bounds__(256) void acc2_kernel(
    const float* __restrict__ p, const float* __restrict__ pw,
    const float* __restrict__ rw, const float* __restrict__ den,
    float* __restrict__ out) {
  int n = blockIdx.x * blockDim.x + threadIdx.x;
  if (n >= NPIX) return;
  int b = n / HW;
  int r = n - b * HW;
  float pwv = pw[n], rwv = rw[n];
  float w = pwv / (rwv + THRESH);
  float scale = w / (pwv + THRESH);
  float d = den[n] + w + EPSV;
  float invd = 1.0f / d;
  int ob = b * 3 * HW + r;
  out[ob + 0 * HW] = (out[ob + 0 * HW] + p[n] * scale) * invd;
  out[ob + 1 * HW] = (out[ob + 1 * HW] + p[NPIX + n] * scale) * invd;
  out[ob + 2 * HW] = (out[ob + 2 * HW] + p[2 * NPIX + n] * scale) * invd;
}

// ---------------------------------------------------------------------------
// Launcher. Workspace layout (floats), 7N total = 103.2 MB:
//   [0, 3N)   p (3 planes); p[0] aliases err scratch (consumed before splat)
//   [3N, 4N)  pw   [4N, 5N)  rw   [5N, 6N)  fw   [6N, 7N)  den (w1)
// No memsets: binned stores fully initialize p/pw/rw before any read.
// ---------------------------------------------------------------------------
extern "C" void kernel_launch(void* const* d_in, const int* in_sizes, int n_in,
                              void* d_out, int out_size, void* d_ws,
                              size_t ws_size, hipStream_t stream) {
  const float* input1 = (const float*)d_in[0];
  const float* input2 = (const float*)d_in[1];
  const float* flow3  = (const float*)d_in[2];
  const float* flow4  = (const float*)d_in[3];
  float* out = (float*)d_out;

  float* ws  = (float*)d_ws;
  float* p   = ws;
  float* err = ws;
  float* pw  = ws + (size_t)3 * NPIX;
  float* rw  = ws + (size_t)4 * NPIX;
  float* fw  = ws + (size_t)5 * NPIX;
  float* den = ws + (size_t)6 * NPIX;

  const int threads = 256;
  const int blocks = (NPIX + threads - 1) / threads;
  dim3 sgrid(WID / GT, HGT / GT, BATCH);  // 80 x 45 x 4, all tiles full

  // ---- branch 1: warp input2 by flow3, compare to input1, splat input1 ----
  err_kernel<<<blocks, threads, 0, stream>>>(input1, input2, flow3, err);
  fw_kernel<<<blocks, threads, 0, stream>>>(err, fw);
  splat_binned_kernel<<<sgrid, threads, 0, stream>>>(flow3, input1, fw, p, pw, rw);
  outlier_kernel<<<blocks, threads, 0, stream>>>(flow3, input1, fw, p, pw, rw);
  acc1_kernel<<<blocks, threads, 0, stream>>>(p, pw, rw, out, den);

  // ---- branch 2: warp input1 by flow4, compare to input2, splat input2 ----
  err_kernel<<<blocks, threads, 0, stream>>>(input2, input1, flow4, err);
  fw_kernel<<<blocks, threads, 0, stream>>>(err, fw);
  splat_binned_kernel<<<sgrid, threads, 0, stream>>>(flow4, input2, fw, p, pw, rw);
  outlier_kernel<<<blocks, threads, 0, stream>>>(flow4, input2, fw, p, pw, rw);
  acc2_kernel<<<blocks, threads, 0, stream>>>(p, pw, rw, den, out);
}

// Round 4
// 558.316 us; speedup vs baseline: 6.0288x; 1.0283x over previous
//
#include <hip/hip_runtime.h>

// Problem constants (match reference setup_inputs / module hyperparams)
#define BATCH 4
#define HGT   720
#define WID   1280
#define HW    (HGT * WID)           // 921600
#define NPIX  (BATCH * HW)          // 3686400
#define NQUAD (NPIX / 4)            // 921600
#define INV2S2 0.22222222222222222f // 1/(2*1.5^2)
#define INV_LAMBDA_E (255.0f / 30.0f)
#define THRESH 1e-6f
#define EPSV   1e-6f

// Binned-gather splat tiling (unchanged from round 3 — 126 us/dispatch,
// VALU-bound). See splat_binned_kernel comment.
#define GT    16
#define GM    5
#define GE    (GT + 2 * GM)   // 26
#define GEC   (GE * GE)       // 676 halo sources per block
#define CUT   4.0f
#define CELLS 19              // floor values t0-2 .. t0+16
#define SCOL  20              // per-row starts: cells 0..18 + row total
#define ECAP  208             // hard max entries per cell-row

// ---------------------------------------------------------------------------
// Kernel 1: photometric error = mean_c |i1 - warp(i2, flow)|   -> err [N]
// float4: 4 px/thread (quads never cross a row: WID % 4 == 0).
// Per-pixel arithmetic identical to the scalar version (bit-exact).
// ---------------------------------------------------------------------------
__global__ __launch_bounds__(256) void err_kernel(
    const float* __restrict__ i1, const float* __restrict__ i2,
    const float* __restrict__ flow, float* __restrict__ err) {
  int q = blockIdx.x * blockDim.x + threadIdx.x;
  if (q >= NQUAD) return;
  int n0 = q * 4;
  int b = n0 / HW;
  int r0 = n0 - b * HW;
  int y = r0 / WID;
  int x0 = r0 - y * WID;

  const float4 uq = *(const float4*)(flow + (size_t)(b * 2 + 0) * HW + r0);
  const float4 vq = *(const float4*)(flow + (size_t)(b * 2 + 1) * HW + r0);
  const float* up = &uq.x;
  const float* vp = &vq.x;
  const float* i2b = i2 + (size_t)b * 3 * HW;
  const float* i1b = i1 + (size_t)b * 3 * HW;

  float4 eo;
  float* ep = &eo.x;
#pragma unroll
  for (int i = 0; i < 4; ++i) {
    int x = x0 + i;
    int r = r0 + i;
    float gx = fminf(fmaxf((float)x + up[i], 0.0f), (float)(WID - 1));
    float gy = fminf(fmaxf((float)y + vp[i], 0.0f), (float)(HGT - 1));
    float x0f = floorf(gx), y0f = floorf(gy);
    int xa = (int)x0f, ya = (int)y0f;
    int xb = min(xa + 1, WID - 1), yb = min(ya + 1, HGT - 1);
    float wx = gx - x0f, wy = gy - y0f;
    float w00 = (1.0f - wx) * (1.0f - wy);
    float w01 = wx * (1.0f - wy);
    float w10 = (1.0f - wx) * wy;
    float w11 = wx * wy;
    int i00 = ya * WID + xa, i01 = ya * WID + xb;
    int i10 = yb * WID + xa, i11 = yb * WID + xb;
    float s = 0.0f;
#pragma unroll
    for (int c = 0; c < 3; ++c) {
      const float* pl = i2b + c * HW;
      float wv = pl[i00] * w00 + pl[i01] * w01 + pl[i10] * w10 + pl[i11] * w11;
      s += fabsf(i1b[c * HW + r] - wv);
    }
    ep[i] = s * (1.0f / 3.0f);
  }
  *(float4*)(err + n0) = eo;
}

// ---------------------------------------------------------------------------
// Kernel 2: 3x3 zero-padded box filter of err, then fw = exp(-(e/LE)^2)
// float4: aligned quad + 2 edge scalars per row; partial sums shared.
// ---------------------------------------------------------------------------
__global__ __launch_bounds__(256) void fw_kernel(
    const float* __restrict__ err, float* __restrict__ fw) {
  int q = blockIdx.x * blockDim.x + threadIdx.x;
  if (q >= NQUAD) return;
  int n0 = q * 4;
  int b = n0 / HW;
  int r0 = n0 - b * HW;
  int y = r0 / WID;
  int x0 = r0 - y * WID;
  const float* e = err + (size_t)b * HW;

  float s0 = 0.f, s1 = 0.f, s2 = 0.f, s3 = 0.f;
#pragma unroll
  for (int dy = -1; dy <= 1; ++dy) {
    int yy = y + dy;
    if (yy < 0 || yy >= HGT) continue;
    const float* row = e + yy * WID;
    float4 qv = *(const float4*)(row + x0);
    float l = (x0 > 0) ? row[x0 - 1] : 0.0f;
    float r = (x0 + 4 < WID) ? row[x0 + 4] : 0.0f;
    s0 += l + qv.x + qv.y;
    s1 += qv.x + qv.y + qv.z;
    s2 += qv.y + qv.z + qv.w;
    s3 += qv.z + qv.w + r;
  }
  float4 o;
  float t;
  t = s0 * (1.0f / 9.0f) * INV_LAMBDA_E; o.x = expf(-t * t);
  t = s1 * (1.0f / 9.0f) * INV_LAMBDA_E; o.y = expf(-t * t);
  t = s2 * (1.0f / 9.0f) * INV_LAMBDA_E; o.z = expf(-t * t);
  t = s3 * (1.0f / 9.0f) * INV_LAMBDA_E; o.w = expf(-t * t);
  *(float4*)(fw + n0) = o;
}

// ---------------------------------------------------------------------------
// Kernel 3: BINNED-gather gaussian splat (unchanged from round 3).
// ---------------------------------------------------------------------------
__global__ __launch_bounds__(256) void splat_binned_kernel(
    const float* __restrict__ flow, const float* __restrict__ img,
    const float* __restrict__ fw, float* __restrict__ p,
    float* __restrict__ pw, float* __restrict__ rw) {
  __shared__ float2 sfrac[GEC];                    //  5408 B
  __shared__ float4 sval[GEC];                     // 10816 B
  __shared__ unsigned short sent[CELLS * ECAP];    //  7904 B
  __shared__ unsigned int scnt[CELLS * CELLS];     //  1444 B
  __shared__ unsigned int sstart[CELLS * SCOL];    //  1520 B   ~27 KB total

  const int b = blockIdx.z;
  const int tx0 = blockIdx.x * GT;
  const int ty0 = blockIdx.y * GT;
  const int ex0 = tx0 - GM;
  const int ey0 = ty0 - GM;
  const float* fu  = flow + (size_t)(b * 2 + 0) * HW;
  const float* fv  = flow + (size_t)(b * 2 + 1) * HW;
  const float* ib  = img + (size_t)b * 3 * HW;
  const float* fwb = fw + (size_t)b * HW;

  // ---- phase 0: zero cell counts ----
  for (int i = threadIdx.x; i < CELLS * CELLS; i += 256) scnt[i] = 0u;
  __syncthreads();

  // ---- phase 1: stage + count (<=3 sources/thread) ----
  int mycell[3];
  unsigned int myofs[3];
#pragma unroll
  for (int t = 0; t < 3; ++t) {
    int cell = -1;
    unsigned int ofs = 0;
    int i = threadIdx.x + t * 256;
    if (i < GEC) {
      int sly = i / GE, slx = i - sly * GE;
      int sx = ex0 + slx, sy = ey0 + sly;
      if (sx >= 0 && sx < WID && sy >= 0 && sy < HGT) {
        int r = sy * WID + sx;
        float u = fu[r], v = fv[r];
        if (fabsf(u) < CUT && fabsf(v) < CUT) {  // complement of outlier path
          float tx = (float)sx + u;
          float ty = (float)sy + v;
          float fx = floorf(tx), fy = floorf(ty);
          int cx = (int)fx - (tx0 - 2);
          int cy = (int)fy - (ty0 - 2);
          if (cx >= 0 && cx < CELLS && cy >= 0 && cy < CELLS) {
            float fwv = fwb[r];
            sfrac[i] = make_float2(tx - fx, ty - fy);
            sval[i] = make_float4(ib[r] * fwv, ib[HW + r] * fwv,
                                  ib[2 * HW + r] * fwv, fwv);
            cell = cy * CELLS + cx;
            ofs = atomicAdd(&scnt[cell], 1u);
          }
        }
      }
    }
    mycell[t] = cell;
    myofs[t] = ofs;
  }
  __syncthreads();

  // ---- phase 2: per-row exclusive prefix over 19 cells (+ row total) ----
  for (int c = threadIdx.x; c < CELLS * SCOL; c += 256) {
    int cy = c / SCOL, cx = c - cy * SCOL;
    unsigned int s = 0;
    for (int q = 0; q < cx; ++q) s += scnt[cy * CELLS + q];
    sstart[c] = s;
  }
  __syncthreads();

  // ---- phase 3: fill entry lists (pos provably < ECAP) ----
#pragma unroll
  for (int t = 0; t < 3; ++t) {
    if (mycell[t] >= 0) {
      int cy = mycell[t] / CELLS, cx = mycell[t] - cy * CELLS;
      unsigned int pos = sstart[cy * SCOL + cx] + myofs[t];
      sent[cy * ECAP + pos] =
          (unsigned short)(((unsigned)cx << 10) | (unsigned)(threadIdx.x + t * 256));
    }
  }
  __syncthreads();

  // ---- phase 4: gather own tap window (4 contiguous ranges) ----
  const int lx = threadIdx.x & 15;
  const int ly = threadIdx.x >> 4;
  float a0 = 0.f, a1 = 0.f, a2 = 0.f, apw = 0.f, arw = 0.f;

#pragma unroll
  for (int k = 0; k < 4; ++k) {
    const int cy = ly + k;                    // cell rows ly..ly+3
    int s = (int)sstart[cy * SCOL + lx];      // cells lx..lx+3 contiguous
    int e = (int)sstart[cy * SCOL + lx + 4];
    const float cky = (float)(2 - k);         // ddy = fracy - (dy-1), dy=3-k
    const int ebase = cy * ECAP;
    for (int j = s; j < e; ++j) {
      unsigned int en = sent[ebase + j];
      int slot = en & 1023;
      int cx = en >> 10;
      float2 fr = sfrac[slot];
      float ddx = fr.x - (float)(lx - cx + 2); // fracx - (dx-1), dx=lx-cx+3
      float ddy = fr.y - cky;
      float g = __expf(-(ddx * ddx + ddy * ddy) * INV2S2);
      float4 vl = sval[slot];
      a0 += vl.x * g;
      a1 += vl.y * g;
      a2 += vl.z * g;
      apw += vl.w * g;
      arw += g;
    }
  }

  // ---- plain coalesced stores: sole owner of this output pixel ----
  const int gi = b * HW + (ty0 + ly) * WID + tx0 + lx;
  p[gi]            = a0;
  p[NPIX + gi]     = a1;
  p[2 * NPIX + gi] = a2;
  pw[gi]           = apw;
  rw[gi]           = arw;
}

// ---------------------------------------------------------------------------
// Kernel 3b: outlier splat — pixels with |flow| >= CUT (~470 px/launch at
// CUT=4.0). float4 scan of flow; rare scalar atomics path.
// ---------------------------------------------------------------------------
__global__ __launch_bounds__(256) void outlier_kernel(
    const float* __restrict__ flow, const float* __restrict__ img,
    const float* __restrict__ fw, float* __restrict__ p,
    float* __restrict__ pw, float* __restrict__ rw) {
  int q = blockIdx.x * blockDim.x + threadIdx.x;
  if (q >= NQUAD) return;
  int n0 = q * 4;
  int b = n0 / HW;
  int r0 = n0 - b * HW;
  const float4 uq = *(const float4*)(flow + (size_t)(b * 2 + 0) * HW + r0);
  const float4 vq = *(const float4*)(flow + (size_t)(b * 2 + 1) * HW + r0);
  const float* up = &uq.x;
  const float* vp = &vq.x;

  bool any = false;
#pragma unroll
  for (int i = 0; i < 4; ++i)
    any |= !(fabsf(up[i]) < CUT && fabsf(vp[i]) < CUT);
  if (!any) return;

  const float* ib = img + (size_t)b * 3 * HW;
  int base = b * HW;
#pragma unroll
  for (int i = 0; i < 4; ++i) {
    float u = up[i], v = vp[i];
    if (fabsf(u) < CUT && fabsf(v) < CUT) continue;
    int r = r0 + i;
    int y = r / WID;
    int x = r - y * WID;
    float txf = (float)x + u, tyf = (float)y + v;
    float fx = floorf(txf), fy = floorf(tyf);
    int ixb = (int)fx, iyb = (int)fy;
    float fracx = txf - fx, fracy = tyf - fy;

    float gxv[4], gyv[4];
#pragma unroll
    for (int d = 0; d < 4; ++d) {
      float ddx = fracx - (float)(d - 1);
      gxv[d] = __expf(-ddx * ddx * INV2S2);
      float ddy = fracy - (float)(d - 1);
      gyv[d] = __expf(-ddy * ddy * INV2S2);
    }

    float fwv = fw[b * HW + r];
    float s0 = ib[0 * HW + r] * fwv;
    float s1 = ib[1 * HW + r] * fwv;
    float s2 = ib[2 * HW + r] * fwv;

    for (int dy = 0; dy < 4; ++dy) {
      int iy = iyb + dy - 1;
      if (iy < 0 || iy >= HGT) continue;
      float gy = gyv[dy];
      for (int dx = 0; dx < 4; ++dx) {
        int ix = ixb + dx - 1;
        if (ix < 0 || ix >= WID) continue;
        float g = gxv[dx] * gy;
        int gi = base + iy * WID + ix;
        atomicAdd(p + gi, s0 * g);
        atomicAdd(p + NPIX + gi, s1 * g);
        atomicAdd(p + 2 * NPIX + gi, s2 * g);
        atomicAdd(pw + gi, fwv * g);
        atomicAdd(rw + gi, g);
      }
    }
  }
}

// ---------------------------------------------------------------------------
// Kernel 4 (fused path): final blend from both branches' splat products.
//   w_i = pw_i/(rw_i+T), s_i = w_i/(pw_i+T)
//   out = (p1*s1 + p2*s2) / (w1 + w2 + EPS)
// float4; eliminates the den/out round trip of the acc1/acc2 path.
// ---------------------------------------------------------------------------
__global__ __launch_bounds__(256) void blend_kernel(
    const float* __restrict__ p1, const float* __restrict__ pw1,
    const float* __restrict__ rw1, const float* __restrict__ p2,
    const float* __restrict__ pw2, const float* __restrict__ rw2,
    float* __restrict__ out) {
  int q = blockIdx.x * blockDim.x + threadIdx.x;
  if (q >= NQUAD) return;
  int n0 = q * 4;
  int b = n0 / HW;
  int r0 = n0 - b * HW;

  float4 pw1v = *(const float4*)(pw1 + n0);
  float4 rw1v = *(const float4*)(rw1 + n0);
  float4 pw2v = *(const float4*)(pw2 + n0);
  float4 rw2v = *(const float4*)(rw2 + n0);
  const float* pw1p = &pw1v.x; const float* rw1p = &rw1v.x;
  const float* pw2p = &pw2v.x; const float* rw2p = &rw2v.x;

  float s1v[4], s2v[4], iv[4];
#pragma unroll
  for (int i = 0; i < 4; ++i) {
    float w1 = pw1p[i] / (rw1p[i] + THRESH);
    float s1 = w1 / (pw1p[i] + THRESH);
    float w2 = pw2p[i] / (rw2p[i] + THRESH);
    float s2 = w2 / (pw2p[i] + THRESH);
    s1v[i] = s1; s2v[i] = s2;
    iv[i] = 1.0f / (w1 + w2 + EPSV);
  }

  size_t ob = (size_t)b * 3 * HW + r0;
#pragma unroll
  for (int c = 0; c < 3; ++c) {
    float4 a = *(const float4*)(p1 + (size_t)c * NPIX + n0);
    float4 bq = *(const float4*)(p2 + (size_t)c * NPIX + n0);
    const float* ap = &a.x; const float* bp = &bq.x;
    float4 o;
    float* op = &o.x;
#pragma unroll
    for (int i = 0; i < 4; ++i)
      op[i] = (ap[i] * s1v[i] + bp[i] * s2v[i]) * iv[i];
    *(float4*)(out + ob + (size_t)c * HW) = o;
  }
}

// ---------------------------------------------------------------------------
// Fallback accumulators (7N workspace path), unchanged semantics.
// ---------------------------------------------------------------------------
__global__ __launch_bounds__(256) void acc1_kernel(
    const float* __restrict__ p, const float* __restrict__ pw,
    const float* __restrict__ rw, float* __restrict__ out,
    float* __restrict__ den) {
  int n = blockIdx.x * blockDim.x + threadIdx.x;
  if (n >= NPIX) return;
  int b = n / HW;
  int r = n - b * HW;
  float pwv = pw[n], rwv = rw[n];
  float w = pwv / (rwv + THRESH);
  den[n] = w;
  float scale = w / (pwv + THRESH);
  int ob = b * 3 * HW + r;
  out[ob + 0 * HW] = p[n] * scale;
  out[ob + 1 * HW] = p[NPIX + n] * scale;
  out[ob + 2 * HW] = p[2 * NPIX + n] * scale;
}

__global__ __launch_bounds__(256) void acc2_kernel(
    const float* __restrict__ p, const float* __restrict__ pw,
    const float* __restrict__ rw, const float* __restrict__ den,
    float* __restrict__ out) {
  int n = blockIdx.x * blockDim.x + threadIdx.x;
  if (n >= NPIX) return;
  int b = n / HW;
  int r = n - b * HW;
  float pwv = pw[n], rwv = rw[n];
  float w = pwv / (rwv + THRESH);
  float scale = w / (pwv + THRESH);
  float d = den[n] + w + EPSV;
  float invd = 1.0f / d;
  int ob = b * 3 * HW + r;
  out[ob + 0 * HW] = (out[ob + 0 * HW] + p[n] * scale) * invd;
  out[ob + 1 * HW] = (out[ob + 1 * HW] + p[NPIX + n] * scale) * invd;
  out[ob + 2 * HW] = (out[ob + 2 * HW] + p[2 * NPIX + n] * scale) * invd;
}

// ---------------------------------------------------------------------------
// Launcher.
// Fused path (ws_size >= 11N floats = 162.2 MB):
//   [0,3N) p1   [3N,4N) pw1  [4N,5N) rw1
//   [5N,8N) p2  [8N,9N) pw2  [9N,10N) rw2   [10N,11N) fw
//   err scratch aliases p2 plane 0 (ws+5N): written by err_kernel, consumed
//   by fw_kernel BEFORE splat writes p2 in both branches.
// Fallback path (>= 7N): round-3 layout with acc1/acc2.
// No memsets: splat owner-stores fully initialize p/pw/rw before any read.
// ---------------------------------------------------------------------------
extern "C" void kernel_launch(void* const* d_in, const int* in_sizes, int n_in,
                              void* d_out, int out_size, void* d_ws,
                              size_t ws_size, hipStream_t stream) {
  const float* input1 = (const float*)d_in[0];
  const float* input2 = (const float*)d_in[1];
  const float* flow3  = (const float*)d_in[2];
  const float* flow4  = (const float*)d_in[3];
  float* out = (float*)d_out;
  float* ws  = (float*)d_ws;

  const int threads = 256;
  const int qblocks = (NQUAD + threads - 1) / threads;   // 3600
  const int nblocks = (NPIX + threads - 1) / threads;
  dim3 sgrid(WID / GT, HGT / GT, BATCH);  // 80 x 45 x 4, all tiles full

  if (ws_size >= (size_t)11 * NPIX * sizeof(float)) {
    float* p1  = ws;
    float* pw1 = ws + (size_t)3 * NPIX;
    float* rw1 = ws + (size_t)4 * NPIX;
    float* p2  = ws + (size_t)5 * NPIX;
    float* pw2 = ws + (size_t)8 * NPIX;
    float* rw2 = ws + (size_t)9 * NPIX;
    float* fw  = ws + (size_t)10 * NPIX;
    float* err = p2;  // plane 0 of p2, consumed before splat writes p2

    // branch 1
    err_kernel<<<qblocks, threads, 0, stream>>>(input1, input2, flow3, err);
    fw_kernel<<<qblocks, threads, 0, stream>>>(err, fw);
    splat_binned_kernel<<<sgrid, threads, 0, stream>>>(flow3, input1, fw, p1, pw1, rw1);
    outlier_kernel<<<qblocks, threads, 0, stream>>>(flow3, input1, fw, p1, pw1, rw1);
    // branch 2
    err_kernel<<<qblocks, threads, 0, stream>>>(input2, input1, flow4, err);
    fw_kernel<<<qblocks, threads, 0, stream>>>(err, fw);
    splat_binned_kernel<<<sgrid, threads, 0, stream>>>(flow4, input2, fw, p2, pw2, rw2);
    outlier_kernel<<<qblocks, threads, 0, stream>>>(flow4, input2, fw, p2, pw2, rw2);
    // fused blend
    blend_kernel<<<qblocks, threads, 0, stream>>>(p1, pw1, rw1, p2, pw2, rw2, out);
  } else {
    float* p   = ws;
    float* err = ws;
    float* pw  = ws + (size_t)3 * NPIX;
    float* rw  = ws + (size_t)4 * NPIX;
    float* fw  = ws + (size_t)5 * NPIX;
    float* den = ws + (size_t)6 * NPIX;

    err_kernel<<<qblocks, threads, 0, stream>>>(input1, input2, flow3, err);
    fw_kernel<<<qblocks, threads, 0, stream>>>(err, fw);
    splat_binned_kernel<<<sgrid, threads, 0, stream>>>(flow3, input1, fw, p, pw, rw);
    outlier_kernel<<<qblocks, threads, 0, stream>>>(flow3, input1, fw, p, pw, rw);
    acc1_kernel<<<nblocks, threads, 0, stream>>>(p, pw, rw, out, den);

    err_kernel<<<qblocks, threads, 0, stream>>>(input2, input1, flow4, err);
    fw_kernel<<<qblocks, threads, 0, stream>>>(err, fw);
    splat_binned_kernel<<<sgrid, threads, 0, stream>>>(flow4, input2, fw, p, pw, rw);
    outlier_kernel<<<qblocks, threads, 0, stream>>>(flow4, input2, fw, p, pw, rw);
    acc2_kernel<<<nblocks, threads, 0, stream>>>(p, pw, rw, den, out);
  }
}

// Round 6
// 526.144 us; speedup vs baseline: 6.3974x; 1.0611x over previous
//
#include <hip/hip_runtime.h>

// Problem constants (match reference setup_inputs / module hyperparams)
#define BATCH 4
#define HGT   720
#define WID   1280
#define HW    (HGT * WID)           // 921600
#define NPIX  (BATCH * HW)          // 3686400
#define NQUAD (NPIX / 4)            // 921600
#define INV2S2 0.22222222222222222f // 1/(2*1.5^2)
#define INV_LAMBDA_E (255.0f / 30.0f)
#define THRESH 1e-6f
#define EPSV   1e-6f

// Binned-gather splat tiling (see splat_binned_kernel).
#define GT    16
#define GM    5
#define GE    (GT + 2 * GM)   // 26
#define GEC   (GE * GE)       // 676 halo sources per block
#define CUT   4.0f
#define CELLS 19              // floor values t0-2 .. t0+16
#define SCOL  20              // per-row starts: cells 0..18 + row total
#define ECAP  208             // hard max entries per cell-row

// err tiling: 16x16 outputs, i2 tile with halo 6 left/top, 7 right/bottom
// (x1 = x0+1). Covers all |u|,|v| < 6; rare lanes fall back to global path.
#define EHL 6
#define EW  29                // 16 + 6 + 7

typedef float v2f __attribute__((ext_vector_type(2)));

// ---------------------------------------------------------------------------
// Kernel 1: photometric error = mean_c |i1 - warp(i2, flow)|   -> err [N]
// LDS-tiled bilinear: stage 29x29x3 of i2 (coalesced), gather from LDS.
// Values read are identical floats to the global path -> bit-exact.
// ---------------------------------------------------------------------------
__global__ __launch_bounds__(256) void err_kernel(
    const float* __restrict__ i1, const float* __restrict__ i2,
    const float* __restrict__ flow, float* __restrict__ err) {
  __shared__ float tile[3][EW * EW + 1];
  const int b = blockIdx.z;
  const int tx0 = blockIdx.x * 16, ty0 = blockIdx.y * 16;
  const int ex0 = tx0 - EHL, ey0 = ty0 - EHL;
  const float* i2b = i2 + (size_t)b * 3 * HW;

  for (int i = threadIdx.x; i < EW * EW; i += 256) {
    int iy = i / EW, ix = i - iy * EW;
    int sx = ex0 + ix, sy = ey0 + iy;
    float c0 = 0.f, c1 = 0.f, c2 = 0.f;
    if (sx >= 0 && sx < WID && sy >= 0 && sy < HGT) {
      int r = sy * WID + sx;
      c0 = i2b[r]; c1 = i2b[HW + r]; c2 = i2b[2 * HW + r];
    }
    tile[0][i] = c0; tile[1][i] = c1; tile[2][i] = c2;
  }
  __syncthreads();

  const int lx = threadIdx.x & 15, ly = threadIdx.x >> 4;
  const int x = tx0 + lx, y = ty0 + ly;
  const int r = y * WID + x;
  float u = flow[(size_t)(b * 2 + 0) * HW + r];
  float v = flow[(size_t)(b * 2 + 1) * HW + r];
  float gx = fminf(fmaxf((float)x + u, 0.0f), (float)(WID - 1));
  float gy = fminf(fmaxf((float)y + v, 0.0f), (float)(HGT - 1));
  float x0f = floorf(gx), y0f = floorf(gy);
  int x0 = (int)x0f, y0 = (int)y0f;
  int x1 = min(x0 + 1, WID - 1), y1 = min(y0 + 1, HGT - 1);
  float wx = gx - x0f, wy = gy - y0f;
  float w00 = (1.0f - wx) * (1.0f - wy);
  float w01 = wx * (1.0f - wy);
  float w10 = (1.0f - wx) * wy;
  float w11 = wx * wy;
  const float* i1b = i1 + (size_t)b * 3 * HW;
  float s = 0.0f;
  if (fabsf(u) < 6.0f && fabsf(v) < 6.0f) {
    // in-tile: x0 in [x-6, x+6] (clamped into image) -> lx0 in [0,27], +1 ok
    int j00 = (y0 - ey0) * EW + (x0 - ex0);
    int jdx = x1 - x0, jdy = (y1 - y0) * EW;
#pragma unroll
    for (int c = 0; c < 3; ++c) {
      float wv = tile[c][j00] * w00 + tile[c][j00 + jdx] * w01 +
                 tile[c][j00 + jdy] * w10 + tile[c][j00 + jdy + jdx] * w11;
      s += fabsf(i1b[c * HW + r] - wv);
    }
  } else {
    int i00 = y0 * WID + x0, i01 = y0 * WID + x1;
    int i10 = y1 * WID + x0, i11 = y1 * WID + x1;
#pragma unroll
    for (int c = 0; c < 3; ++c) {
      const float* pl = i2b + c * HW;
      float wv = pl[i00] * w00 + pl[i01] * w01 + pl[i10] * w10 + pl[i11] * w11;
      s += fabsf(i1b[c * HW + r] - wv);
    }
  }
  err[(size_t)b * HW + r] = s * (1.0f / 3.0f);
}

// ---------------------------------------------------------------------------
// Kernel 2: 3x3 zero-padded box filter of err, then fw = exp(-(e/LE)^2)
// float4: aligned quad + 2 edge scalars per row; partial sums shared.
// ---------------------------------------------------------------------------
__global__ __launch_bounds__(256) void fw_kernel(
    const float* __restrict__ err, float* __restrict__ fw) {
  int q = blockIdx.x * blockDim.x + threadIdx.x;
  if (q >= NQUAD) return;
  int n0 = q * 4;
  int b = n0 / HW;
  int r0 = n0 - b * HW;
  int y = r0 / WID;
  int x0 = r0 - y * WID;
  const float* e = err + (size_t)b * HW;

  float s0 = 0.f, s1 = 0.f, s2 = 0.f, s3 = 0.f;
#pragma unroll
  for (int dy = -1; dy <= 1; ++dy) {
    int yy = y + dy;
    if (yy < 0 || yy >= HGT) continue;
    const float* row = e + yy * WID;
    float4 qv = *(const float4*)(row + x0);
    float l = (x0 > 0) ? row[x0 - 1] : 0.0f;
    float r = (x0 + 4 < WID) ? row[x0 + 4] : 0.0f;
    s0 += l + qv.x + qv.y;
    s1 += qv.x + qv.y + qv.z;
    s2 += qv.y + qv.z + qv.w;
    s3 += qv.z + qv.w + r;
  }
  float4 o;
  float t;
  t = s0 * (1.0f / 9.0f) * INV_LAMBDA_E; o.x = expf(-t * t);
  t = s1 * (1.0f / 9.0f) * INV_LAMBDA_E; o.y = expf(-t * t);
  t = s2 * (1.0f / 9.0f) * INV_LAMBDA_E; o.z = expf(-t * t);
  t = s3 * (1.0f / 9.0f) * INV_LAMBDA_E; o.w = expf(-t * t);
  *(float4*)(fw + n0) = o;
}

// ---------------------------------------------------------------------------
// Kernel 3: BINNED-gather gaussian splat.
// Inner-loop diet: stage per-slot fx' = fracx + cx, fy' = fracy - 2
// so the gather computes ddx = fx' - (lx+2), ddy = fy' + k (one VALU op
// each; no cx decode, no int->float cvt). sent stores the bare slot.
// fx' rounds once (err <= 2^-20 rel -> g moves ~1e-5, negligible).
// Accumulators paired as v2f to invite v_pk_fma_f32.
// ---------------------------------------------------------------------------
__global__ __launch_bounds__(256) void splat_binned_kernel(
    const float* __restrict__ flow, const float* __restrict__ img,
    const float* __restrict__ fw, float* __restrict__ p,
    float* __restrict__ pw, float* __restrict__ rw) {
  __shared__ float2 sfp[GEC];                      //  5408 B (fx', fy')
  __shared__ float4 sval[GEC];                     // 10816 B
  __shared__ unsigned short sent[CELLS * ECAP];    //  7904 B (slot only)
  __shared__ unsigned int scnt[CELLS * CELLS];     //  1444 B
  __shared__ unsigned int sstart[CELLS * SCOL];    //  1520 B   ~27 KB total

  const int b = blockIdx.z;
  const int tx0 = blockIdx.x * GT;
  const int ty0 = blockIdx.y * GT;
  const int ex0 = tx0 - GM;
  const int ey0 = ty0 - GM;
  const float* fu  = flow + (size_t)(b * 2 + 0) * HW;
  const float* fv  = flow + (size_t)(b * 2 + 1) * HW;
  const float* ib  = img + (size_t)b * 3 * HW;
  const float* fwb = fw + (size_t)b * HW;

  // ---- phase 0: zero cell counts ----
  for (int i = threadIdx.x; i < CELLS * CELLS; i += 256) scnt[i] = 0u;
  __syncthreads();

  // ---- phase 1: stage + count (<=3 sources/thread) ----
  int mycell[3];
  unsigned int myofs[3];
#pragma unroll
  for (int t = 0; t < 3; ++t) {
    int cell = -1;
    unsigned int ofs = 0;
    int i = threadIdx.x + t * 256;
    if (i < GEC) {
      int sly = i / GE, slx = i - sly * GE;
      int sx = ex0 + slx, sy = ey0 + sly;
      if (sx >= 0 && sx < WID && sy >= 0 && sy < HGT) {
        int r = sy * WID + sx;
        float u = fu[r], v = fv[r];
        if (fabsf(u) < CUT && fabsf(v) < CUT) {  // complement of outlier path
          float tx = (float)sx + u;
          float ty = (float)sy + v;
          float fx = floorf(tx), fy = floorf(ty);
          int cx = (int)fx - (tx0 - 2);
          int cy = (int)fy - (ty0 - 2);
          if (cx >= 0 && cx < CELLS && cy >= 0 && cy < CELLS) {
            float fwv = fwb[r];
            sfp[i] = make_float2((tx - fx) + (float)cx, (ty - fy) - 2.0f);
            sval[i] = make_float4(ib[r] * fwv, ib[HW + r] * fwv,
                                  ib[2 * HW + r] * fwv, fwv);
            cell = cy * CELLS + cx;
            ofs = atomicAdd(&scnt[cell], 1u);
          }
        }
      }
    }
    mycell[t] = cell;
    myofs[t] = ofs;
  }
  __syncthreads();

  // ---- phase 2: per-row exclusive prefix over 19 cells (+ row total) ----
  for (int c = threadIdx.x; c < CELLS * SCOL; c += 256) {
    int cy = c / SCOL, cx = c - cy * SCOL;
    unsigned int s = 0;
    for (int q = 0; q < cx; ++q) s += scnt[cy * CELLS + q];
    sstart[c] = s;
  }
  __syncthreads();

  // ---- phase 3: fill entry lists (pos provably < ECAP) ----
#pragma unroll
  for (int t = 0; t < 3; ++t) {
    if (mycell[t] >= 0) {
      int cy = mycell[t] / CELLS, cx = mycell[t] - cy * CELLS;
      unsigned int pos = sstart[cy * SCOL + cx] + myofs[t];
      sent[cy * ECAP + pos] = (unsigned short)(threadIdx.x + t * 256);
    }
  }
  __syncthreads();

  // ---- phase 4: gather own tap window (4 contiguous ranges) ----
  const int lx = threadIdx.x & 15;
  const int ly = threadIdx.x >> 4;
  const float Lx2 = (float)(lx + 2);
  v2f a01 = {0.f, 0.f}, a2w = {0.f, 0.f};
  float arw = 0.f;

#pragma unroll
  for (int k = 0; k < 4; ++k) {
    const int cy = ly + k;                    // cell rows ly..ly+3
    int s = (int)sstart[cy * SCOL + lx];      // cells lx..lx+3 contiguous
    int e = (int)sstart[cy * SCOL + lx + 4];
    const float kf = (float)k;                // ddy = (fracy-2) + k
    const int ebase = cy * ECAP;
    for (int j = s; j < e; ++j) {
      int slot = sent[ebase + j];
      float2 fp = sfp[slot];
      float ddx = fp.x - Lx2;                 // fracx - (lx-cx+2)
      float ddy = fp.y + kf;
      float g = __expf(-(ddx * ddx + ddy * ddy) * INV2S2);
      float4 vl = sval[slot];
      v2f g2 = {g, g};
      v2f v01 = {vl.x, vl.y};
      v2f v2w = {vl.z, vl.w};
      a01 += v01 * g2;
      a2w += v2w * g2;
      arw += g;
    }
  }

  // ---- plain coalesced stores: sole owner of this output pixel ----
  const int gi = b * HW + (ty0 + ly) * WID + tx0 + lx;
  p[gi]            = a01.x;
  p[NPIX + gi]     = a01.y;
  p[2 * NPIX + gi] = a2w.x;
  pw[gi]           = a2w.y;
  rw[gi]           = arw;
}

// ---------------------------------------------------------------------------
// Kernel 3b: outlier splat — pixels with |flow| >= CUT (~470 px/launch at
// CUT=4.0). float4 scan of flow; rare scalar atomics path.
// ---------------------------------------------------------------------------
__global__ __launch_bounds__(256) void outlier_kernel(
    const float* __restrict__ flow, const float* __restrict__ img,
    const float* __restrict__ fw, float* __restrict__ p,
    float* __restrict__ pw, float* __restrict__ rw) {
  int q = blockIdx.x * blockDim.x + threadIdx.x;
  if (q >= NQUAD) return;
  int n0 = q * 4;
  int b = n0 / HW;
  int r0 = n0 - b * HW;
  const float4 uq = *(const float4*)(flow + (size_t)(b * 2 + 0) * HW + r0);
  const float4 vq = *(const float4*)(flow + (size_t)(b * 2 + 1) * HW + r0);
  const float* up = &uq.x;
  const float* vp = &vq.x;

  bool any = false;
#pragma unroll
  for (int i = 0; i < 4; ++i)
    any |= !(fabsf(up[i]) < CUT && fabsf(vp[i]) < CUT);
  if (!any) return;

  const float* ib = img + (size_t)b * 3 * HW;
  int base = b * HW;
#pragma unroll
  for (int i = 0; i < 4; ++i) {
    float u = up[i], v = vp[i];
    if (fabsf(u) < CUT && fabsf(v) < CUT) continue;
    int r = r0 + i;
    int y = r / WID;
    int x = r - y * WID;
    float txf = (float)x + u, tyf = (float)y + v;
    float fx = floorf(txf), fy = floorf(tyf);
    int ixb = (int)fx, iyb = (int)fy;
    float fracx = txf - fx, fracy = tyf - fy;

    float gxv[4], gyv[4];
#pragma unroll
    for (int d = 0; d < 4; ++d) {
      float ddx = fracx - (float)(d - 1);
      gxv[d] = __expf(-ddx * ddx * INV2S2);
      float ddy = fracy - (float)(d - 1);
      gyv[d] = __expf(-ddy * ddy * INV2S2);
    }

    float fwv = fw[b * HW + r];
    float s0 = ib[0 * HW + r] * fwv;
    float s1 = ib[1 * HW + r] * fwv;
    float s2 = ib[2 * HW + r] * fwv;

    for (int dy = 0; dy < 4; ++dy) {
      int iy = iyb + dy - 1;
      if (iy < 0 || iy >= HGT) continue;
      float gy = gyv[dy];
      for (int dx = 0; dx < 4; ++dx) {
        int ix = ixb + dx - 1;
        if (ix < 0 || ix >= WID) continue;
        float g = gxv[dx] * gy;
        int gi = base + iy * WID + ix;
        atomicAdd(p + gi, s0 * g);
        atomicAdd(p + NPIX + gi, s1 * g);
        atomicAdd(p + 2 * NPIX + gi, s2 * g);
        atomicAdd(pw + gi, fwv * g);
        atomicAdd(rw + gi, g);
      }
    }
  }
}

// ---------------------------------------------------------------------------
// Kernel 4 (fused path): final blend from both branches' splat products.
//   w_i = pw_i/(rw_i+T), s_i = w_i/(pw_i+T)
//   out = (p1*s1 + p2*s2) / (w1 + w2 + EPS)
// ---------------------------------------------------------------------------
__global__ __launch_bounds__(256) void blend_kernel(
    const float* __restrict__ p1, const float* __restrict__ pw1,
    const float* __restrict__ rw1, const float* __restrict__ p2,
    const float* __restrict__ pw2, const float* __restrict__ rw2,
    float* __restrict__ out) {
  int q = blockIdx.x * blockDim.x + threadIdx.x;
  if (q >= NQUAD) return;
  int n0 = q * 4;
  int b = n0 / HW;
  int r0 = n0 - b * HW;

  float4 pw1v = *(const float4*)(pw1 + n0);
  float4 rw1v = *(const float4*)(rw1 + n0);
  float4 pw2v = *(const float4*)(pw2 + n0);
  float4 rw2v = *(const float4*)(rw2 + n0);
  const float* pw1p = &pw1v.x; const float* rw1p = &rw1v.x;
  const float* pw2p = &pw2v.x; const float* rw2p = &rw2v.x;

  float s1v[4], s2v[4], iv[4];
#pragma unroll
  for (int i = 0; i < 4; ++i) {
    float w1 = pw1p[i] / (rw1p[i] + THRESH);
    float s1 = w1 / (pw1p[i] + THRESH);
    float w2 = pw2p[i] / (rw2p[i] + THRESH);
    float s2 = w2 / (pw2p[i] + THRESH);
    s1v[i] = s1; s2v[i] = s2;
    iv[i] = 1.0f / (w1 + w2 + EPSV);
  }

  size_t ob = (size_t)b * 3 * HW + r0;
#pragma unroll
  for (int c = 0; c < 3; ++c) {
    float4 a = *(const float4*)(p1 + (size_t)c * NPIX + n0);
    float4 bq = *(const float4*)(p2 + (size_t)c * NPIX + n0);
    const float* ap = &a.x; const float* bp = &bq.x;
    float4 o;
    float* op = &o.x;
#pragma unroll
    for (int i = 0; i < 4; ++i)
      op[i] = (ap[i] * s1v[i] + bp[i] * s2v[i]) * iv[i];
    *(float4*)(out + ob + (size_t)c * HW) = o;
  }
}

// ---------------------------------------------------------------------------
// Fallback accumulators (7N workspace path), float4-vectorized.
// ---------------------------------------------------------------------------
__global__ __launch_bounds__(256) void acc1_kernel(
    const float* __restrict__ p, const float* __restrict__ pw,
    const float* __restrict__ rw, float* __restrict__ out,
    float* __restrict__ den) {
  int q = blockIdx.x * blockDim.x + threadIdx.x;
  if (q >= NQUAD) return;
  int n0 = q * 4;
  int b = n0 / HW;
  int r0 = n0 - b * HW;
  float4 pwv = *(const float4*)(pw + n0);
  float4 rwv = *(const float4*)(rw + n0);
  const float* pwp = &pwv.x; const float* rwp = &rwv.x;
  float4 wv; float* wp = &wv.x;
  float sv[4];
#pragma unroll
  for (int i = 0; i < 4; ++i) {
    float w = pwp[i] / (rwp[i] + THRESH);
    wp[i] = w;
    sv[i] = w / (pwp[i] + THRESH);
  }
  *(float4*)(den + n0) = wv;
  size_t ob = (size_t)b * 3 * HW + r0;
#pragma unroll
  for (int c = 0; c < 3; ++c) {
    float4 a = *(const float4*)(p + (size_t)c * NPIX + n0);
    const float* ap = &a.x;
    float4 o; float* op = &o.x;
#pragma unroll
    for (int i = 0; i < 4; ++i) op[i] = ap[i] * sv[i];
    *(float4*)(out + ob + (size_t)c * HW) = o;
  }
}

__global__ __launch_bounds__(256) void acc2_kernel(
    const float* __restrict__ p, const float* __restrict__ pw,
    const float* __restrict__ rw, const float* __restrict__ den,
    float* __restrict__ out) {
  int q = blockIdx.x * blockDim.x + threadIdx.x;
  if (q >= NQUAD) return;
  int n0 = q * 4;
  int b = n0 / HW;
  int r0 = n0 - b * HW;
  float4 pwv = *(const float4*)(pw + n0);
  float4 rwv = *(const float4*)(rw + n0);
  float4 dnv = *(const float4*)(den + n0);
  const float* pwp = &pwv.x; const float* rwp = &rwv.x;
  const float* dnp = &dnv.x;
  float sv[4], iv[4];
#pragma unroll
  for (int i = 0; i < 4; ++i) {
    float w = pwp[i] / (rwp[i] + THRESH);
    sv[i] = w / (pwp[i] + THRESH);
    iv[i] = 1.0f / (dnp[i] + w + EPSV);
  }
  size_t ob = (size_t)b * 3 * HW + r0;
#pragma unroll
  for (int c = 0; c < 3; ++c) {
    float4 a = *(const float4*)(p + (size_t)c * NPIX + n0);
    float4 o = *(const float4*)(out + ob + (size_t)c * HW);
    const float* ap = &a.x; float* op = &o.x;
#pragma unroll
    for (int i = 0; i < 4; ++i) op[i] = (op[i] + ap[i] * sv[i]) * iv[i];
    *(float4*)(out + ob + (size_t)c * HW) = o;
  }
}

// ---------------------------------------------------------------------------
// Launcher.
// Fused path (ws_size >= 11N floats): both branches resident + single blend.
// Fallback path (>= 7N): acc1/acc2 with out+den round trip.
// err scratch aliases a p-plane consumed before the corresponding splat.
// ---------------------------------------------------------------------------
extern "C" void kernel_launch(void* const* d_in, const int* in_sizes, int n_in,
                              void* d_out, int out_size, void* d_ws,
                              size_t ws_size, hipStream_t stream) {
  const float* input1 = (const float*)d_in[0];
  const float* input2 = (const float*)d_in[1];
  const float* flow3  = (const float*)d_in[2];
  const float* flow4  = (const float*)d_in[3];
  float* out = (float*)d_out;
  float* ws  = (float*)d_ws;

  const int threads = 256;
  const int qblocks = (NQUAD + threads - 1) / threads;   // 3600
  dim3 sgrid(WID / GT, HGT / GT, BATCH);  // 80 x 45 x 4, all tiles full
  dim3 egrid(WID / 16, HGT / 16, BATCH);  // err tiling

  if (ws_size >= (size_t)11 * NPIX * sizeof(float)) {
    float* p1  = ws;
    float* pw1 = ws + (size_t)3 * NPIX;
    float* rw1 = ws + (size_t)4 * NPIX;
    float* p2  = ws + (size_t)5 * NPIX;
    float* pw2 = ws + (size_t)8 * NPIX;
    float* rw2 = ws + (size_t)9 * NPIX;
    float* fw  = ws + (size_t)10 * NPIX;
    float* err = p2;  // plane 0 of p2, consumed before splat writes p2

    // branch 1
    err_kernel<<<egrid, threads, 0, stream>>>(input1, input2, flow3, err);
    fw_kernel<<<qblocks, threads, 0, stream>>>(err, fw);
    splat_binned_kernel<<<sgrid, threads, 0, stream>>>(flow3, input1, fw, p1, pw1, rw1);
    outlier_kernel<<<qblocks, threads, 0, stream>>>(flow3, input1, fw, p1, pw1, rw1);
    // branch 2
    err_kernel<<<egrid, threads, 0, stream>>>(input2, input1, flow4, err);
    fw_kernel<<<qblocks, threads, 0, stream>>>(err, fw);
    splat_binned_kernel<<<sgrid, threads, 0, stream>>>(flow4, input2, fw, p2, pw2, rw2);
    outlier_kernel<<<qblocks, threads, 0, stream>>>(flow4, input2, fw, p2, pw2, rw2);
    // fused blend
    blend_kernel<<<qblocks, threads, 0, stream>>>(p1, pw1, rw1, p2, pw2, rw2, out);
  } else {
    float* p   = ws;
    float* err = ws;
    float* pw  = ws + (size_t)3 * NPIX;
    float* rw  = ws + (size_t)4 * NPIX;
    float* fw  = ws + (size_t)5 * NPIX;
    float* den = ws + (size_t)6 * NPIX;

    err_kernel<<<egrid, threads, 0, stream>>>(input1, input2, flow3, err);
    fw_kernel<<<qblocks, threads, 0, stream>>>(err, fw);
    splat_binned_kernel<<<sgrid, threads, 0, stream>>>(flow3, input1, fw, p, pw, rw);
    outlier_kernel<<<qblocks, threads, 0, stream>>>(flow3, input1, fw, p, pw, rw);
    acc1_kernel<<<qblocks, threads, 0, stream>>>(p, pw, rw, out, den);

    err_kernel<<<egrid, threads, 0, stream>>>(input2, input1, flow4, err);
    fw_kernel<<<qblocks, threads, 0, stream>>>(err, fw);
    splat_binned_kernel<<<sgrid, threads, 0, stream>>>(flow4, input2, fw, p, pw, rw);
    outlier_kernel<<<qblocks, threads, 0, stream>>>(flow4, input2, fw, p, pw, rw);
    acc2_kernel<<<qblocks, threads, 0, stream>>>(p, pw, rw, den, out);
  }
}